// Round 7
// baseline (212.576 us; speedup 1.0000x reference)
//
#include <hip/hip_runtime.h>

// PlatonicConv: linear attention with tetrahedral-group RoPE.
// N=32768 nodes, C=E=384, G=12 groups, H=1, D=32, P=16, 64 graphs (batch sorted).
// I/O fp32; internal bf16 MFMA with fp32 accumulate.
//
// Round 14: round-13 dbuf REGRESSED (202.7 vs 195.2: __syncthreads drains
// vmcnt(0) incl. the prefetch -> zero overlap, m99/m100 precedent). Core
// reverted to round-11 verified BK=64 single-buffer.
// This round: xb round-trip deleted. gemm_qv stages fp32 x directly into LDS
// (A-region 32KB fp32 [128][64], same 1024B-segment glds scheme) and converts
// bf16 during LDS->fragment load via v_cvt_pk_bf16_f32 (RNE == f2bf, 4 packs
// per fragment). prep shrinks to 432 transpose blocks; ~100 MB -> ~50 MB
// HBM for the x path.
// Pipeline (5 dispatches): prep(W-T only), gemm_qv(fp32-A), kv_mfma,
// attn_mfma, gemm_out.

#define N_NODES 32768
#define K_DIM   384
#define P_PAIR  16
#define NUM_GRAPHS 64

typedef unsigned short u16;
typedef __bf16 bf16x8 __attribute__((ext_vector_type(8)));
typedef float  f32x4  __attribute__((ext_vector_type(4)));
typedef float  f32x16 __attribute__((ext_vector_type(16)));
typedef __attribute__((address_space(3))) void       lds_void;
typedef const __attribute__((address_space(1))) void gbl_void;

__device__ __forceinline__ u16 f2bf(float f) {
    unsigned int i = __float_as_uint(f);
    unsigned int r = i + 0x7FFFu + ((i >> 16) & 1u);   // RNE
    return (u16)(r >> 16);
}
__device__ __forceinline__ float bf2f(u16 u) {
    union { unsigned int i; float f; } x;
    x.i = ((unsigned int)u) << 16;
    return x.f;
}

// ---------------------------------------------------------------------------
// prep: W transposes only (xb path deleted).  432 blocks = 3 matrices x 144
// 32x32 tiles: WqvT[n][k]=[Wq|Wv][k][n], WoT[n][k]=Wo[k][n].
__global__ void prep(const float* __restrict__ Wq, const float* __restrict__ Wv,
                     const float* __restrict__ Wo,
                     u16* __restrict__ WqvT, u16* __restrict__ WoT) {
    __shared__ float ld[32][33];
    const int tb  = blockIdx.x;
    const int mat = tb / 144;                    // 0: Wq, 1: Wv, 2: Wo
    const int tl  = tb % 144;
    const int tr  = tl / 12, tc = tl % 12;       // src tile row (k), col (n)
    const float* src = (mat == 0) ? Wq : (mat == 1) ? Wv : Wo;
    u16* dst = (mat == 2) ? WoT : WqvT;
    const int n_off = (mat == 1) ? 384 : 0;

    const int t = threadIdx.x;
    const int c = t & 31, r = t >> 5;            // 8 rows per pass
#pragma unroll
    for (int i = 0; i < 4; i++) {
        int r0 = r + (i << 3);
        ld[r0][c] = src[(tr * 32 + r0) * 384 + tc * 32 + c];
    }
    __syncthreads();
    const int ck = t & 31;
#pragma unroll
    for (int i = 0; i < 4; i++) {
        int cn = r + (i << 3);
        dst[(size_t)(n_off + tc * 32 + cn) * 384 + tr * 32 + ck] = f2bf(ld[ck][cn]);
    }
}

// ---------------------------------------------------------------------------
// Shared GEMM core (bf16 A+B, used by gemm_out): 128x128 tile, BK=64 as four
// 128x32 sub-tiles [A0|A1|B0|B1], each 4096 u16, staged via glds w16 in 8
// segments of 1024B apiece.  4 waves 2x2, 4x4 16x16x32 MFMA, two k-halves per
// K-step.  ROUND-11 VERIFIED.
#define GEMM_CORE(A_PTR, B_PTR)                                                  \
    __shared__ __align__(1024) u16 T[16384];                                     \
    const int tid = threadIdx.x;                                                 \
    const int w = tid >> 6, lane = tid & 63;                                     \
    const int wr = (w >> 1) << 6, wc = (w & 1) << 6;                             \
    const int lm = lane & 15, q = lane >> 4;                                     \
    const int srow = lane >> 2, sc8 = (lane & 3) << 3;                           \
    f32x4 acc[4][4];                                                             \
    _Pragma("unroll") for (int i = 0; i < 4; i++)                                \
    _Pragma("unroll") for (int j = 0; j < 4; j++)                                \
    _Pragma("unroll") for (int r = 0; r < 4; r++) acc[i][j][r] = 0.0f;           \
    for (int k0 = 0; k0 < K_DIM; k0 += 64) {                                     \
        __syncthreads();                                                         \
        _Pragma("unroll")                                                        \
        for (int s = w; s < 32; s += 4) {                                        \
            int row  = ((s & 7) << 4) + srow;                                    \
            int half = (s >> 3) & 1;                                             \
            const u16* gp = ((s >> 4) ? (B_PTR) + (size_t)(n0 + row) * K_DIM     \
                                      : (A_PTR) + (size_t)(m0 + row) * K_DIM)    \
                            + k0 + (half << 5) + sc8;                            \
            __builtin_amdgcn_global_load_lds((gbl_void*)gp,                      \
                                             (lds_void*)&T[s << 9], 16, 0, 0);   \
        }                                                                        \
        __syncthreads();                                                         \
        _Pragma("unroll")                                                        \
        for (int h = 0; h < 2; h++) {                                            \
            bf16x8 af[4], bfr[4];                                                \
            _Pragma("unroll") for (int i = 0; i < 4; i++) {                      \
                af[i]  = *reinterpret_cast<const bf16x8*>(                       \
                    &T[(h << 12) + (wr + i * 16 + lm) * 32 + q * 8]);            \
                bfr[i] = *reinterpret_cast<const bf16x8*>(                       \
                    &T[8192 + (h << 12) + (wc + i * 16 + lm) * 32 + q * 8]);     \
            }                                                                    \
            _Pragma("unroll") for (int i = 0; i < 4; i++)                        \
            _Pragma("unroll") for (int j = 0; j < 4; j++)                        \
                acc[i][j] = __builtin_amdgcn_mfma_f32_16x16x32_bf16(             \
                    af[i], bfr[j], acc[i][j], 0, 0, 0);                          \
        }                                                                        \
    }

// ---------------------------------------------------------------------------
// [Q|V] = bf16(x) @ [Wq|Wv]^T + [bq|bv], fp32 x staged directly.
// A-region: 32KB fp32 [128][64] (32 segments of 1024B; segment s covers rows
// 4s..4s+3, lane l -> row 4s+(l>>4), cols 4(l&15)..+4).  B-region: bf16
// [2][128][32] at byte 32768 (verified round-11 layout).  Fragment A: two
// ds_read_b128 + 4 v_cvt_pk_bf16_f32 (RNE == f2bf -> bit-identical values).
__global__ __launch_bounds__(256) void gemm_qv(
    const float* __restrict__ X, const u16* __restrict__ Bt,
    const float* __restrict__ bq, const float* __restrict__ bv,
    u16* __restrict__ Qw, u16* __restrict__ Vd) {
    const int b = blockIdx.x;                 // 1536 blocks
    const int xcd = b & 7, jj = b >> 3;       // jj 0..191
    const int by = xcd * 32 + jj / 6, bx = jj % 6;
    const int m0 = by << 7, n0 = bx << 7;

    __shared__ __align__(1024) u16 T[24576];  // [0,32KB): A fp32; [32,48KB): B bf16
    float* Af = reinterpret_cast<float*>(T);
    const int tid = threadIdx.x;
    const int w = tid >> 6, lane = tid & 63;
    const int wr = (w >> 1) << 6, wc = (w & 1) << 6;
    const int lm = lane & 15, q = lane >> 4;
    const int srow = lane >> 2, sc8 = (lane & 3) << 3;
    const int arow = lane >> 4, ac4 = (lane & 15) << 2;

    f32x4 acc[4][4];
#pragma unroll
    for (int i = 0; i < 4; i++)
#pragma unroll
    for (int j = 0; j < 4; j++)
#pragma unroll
    for (int r = 0; r < 4; r++) acc[i][j][r] = 0.0f;

    for (int k0 = 0; k0 < K_DIM; k0 += 64) {
        __syncthreads();
        // stage A (fp32 x): 32 segments x 1024B
#pragma unroll
        for (int s = w; s < 32; s += 4) {
            const float* gp = X + (size_t)(m0 + (s << 2) + arow) * K_DIM + k0 + ac4;
            __builtin_amdgcn_global_load_lds((gbl_void*)gp,
                                             (lds_void*)&Af[s << 8], 16, 0, 0);
        }
        // stage B (bf16 WqvT): 16 segments x 1024B
#pragma unroll
        for (int s = w; s < 16; s += 4) {
            int row  = ((s & 7) << 4) + srow;
            int half = (s >> 3) & 1;
            const u16* gp = Bt + (size_t)(n0 + row) * K_DIM + k0 + (half << 5) + sc8;
            __builtin_amdgcn_global_load_lds((gbl_void*)gp,
                                             (lds_void*)&T[16384 + (s << 9)], 16, 0, 0);
        }
        __syncthreads();
#pragma unroll
        for (int h = 0; h < 2; h++) {
            bf16x8 af[4], bfr[4];
#pragma unroll
            for (int i = 0; i < 4; i++) {
                const float* ap = &Af[(wr + i * 16 + lm) * 64 + (h << 5) + q * 8];
                f32x4 a0 = *reinterpret_cast<const f32x4*>(ap);
                f32x4 a1 = *reinterpret_cast<const f32x4*>(ap + 4);
                union { bf16x8 v; unsigned int u[4]; } pk;
                asm("v_cvt_pk_bf16_f32 %0, %1, %2" : "=v"(pk.u[0]) : "v"(a0[0]), "v"(a0[1]));
                asm("v_cvt_pk_bf16_f32 %0, %1, %2" : "=v"(pk.u[1]) : "v"(a0[2]), "v"(a0[3]));
                asm("v_cvt_pk_bf16_f32 %0, %1, %2" : "=v"(pk.u[2]) : "v"(a1[0]), "v"(a1[1]));
                asm("v_cvt_pk_bf16_f32 %0, %1, %2" : "=v"(pk.u[3]) : "v"(a1[2]), "v"(a1[3]));
                af[i] = pk.v;
                bfr[i] = *reinterpret_cast<const bf16x8*>(
                    &T[16384 + (h << 12) + (wc + i * 16 + lm) * 32 + q * 8]);
            }
#pragma unroll
            for (int i = 0; i < 4; i++)
#pragma unroll
            for (int j = 0; j < 4; j++)
                acc[i][j] = __builtin_amdgcn_mfma_f32_16x16x32_bf16(
                    af[i], bfr[j], acc[i][j], 0, 0, 0);
        }
    }
    // C/D layout: col = lane&15, row = (lane>>4)*4 + r  [HW-confirmed]
    u16* Cq = (n0 < 384) ? Qw : Vd;
    const float* bias = (n0 < 384) ? bq : bv;
    const int coff = (n0 < 384) ? 0 : 384;
#pragma unroll
    for (int j = 0; j < 4; j++) {
        int gc = n0 + wc + j * 16 + lm - coff;
        float bs = bias[gc];
#pragma unroll
        for (int i = 0; i < 4; i++) {
            int gr = m0 + wr + i * 16 + q * 4;
#pragma unroll
            for (int r = 0; r < 4; r++)
                Cq[(size_t)(gr + r) * 384 + gc] = f2bf(acc[i][j][r] + bs);
        }
    }
}

// ---------------------------------------------------------------------------
// out = O @ Wo^T + bo (fp32 out).  O = attn output, in-place over Qw.
__global__ __launch_bounds__(256) void gemm_out(
    const u16* __restrict__ A, const u16* __restrict__ Bt,
    const float* __restrict__ bias, float* __restrict__ Cmat) {
    const int b = blockIdx.x;                 // 768 blocks
    const int xcd = b & 7, jj = b >> 3;       // jj 0..95
    const int by = xcd * 32 + jj / 3, bx = jj % 3;
    const int m0 = by << 7, n0 = bx << 7;
    GEMM_CORE(A, Bt)
#pragma unroll
    for (int j = 0; j < 4; j++) {
        int gc = n0 + wc + j * 16 + lm;
        float bs = bias[gc];
#pragma unroll
        for (int i = 0; i < 4; i++) {
            int gr = m0 + wr + i * 16 + q * 4;
#pragma unroll
            for (int r = 0; r < 4; r++)
                Cmat[(size_t)(gr + r) * 384 + gc] = acc[i][j][r] + bs;
        }
    }
}

// ---------------------------------------------------------------------------
// kv_mfma: KV[g][grp][d][e] = (1/512) sum_{n in graph g} k[n][grp][d] v[n][grp][e]
// One block per (g, grp): 768 blocks x 256 threads (4 waves), 32x32xK MFMA
// over the graph's nodes.  k = rope(ones).  fp32 flat [d][e] output. VERIFIED.
__global__ __launch_bounds__(256) void kv_mfma(
    const u16* __restrict__ V, const float* __restrict__ pos,
    const int* __restrict__ batch, const float* __restrict__ freqs,
    float* __restrict__ KV) {
    const int bid = blockIdx.x;               // 768 = 64 graphs * 12 groups
    const int xcd = bid & 7, jj = bid >> 3;   // jj 0..95
    const int g = (xcd << 3) + jj / 12, grp = jj % 12;

    const int tid = threadIdx.x;
    const int w = tid >> 6, lane = tid & 63;
    const int hi = lane >> 5, de = lane & 31; // A-row d == B-col e == de
    const int p = de >> 1, sgn = de & 1;

    const float f0 = freqs[(grp * P_PAIR + p) * 3 + 0];
    const float f1 = freqs[(grp * P_PAIR + p) * 3 + 1];
    const float f2 = freqs[(grp * P_PAIR + p) * 3 + 2];

    // segment bounds (uniform across block)
    int s0 = 0, s1 = N_NODES;
    while (s0 < s1) { int m = (s0 + s1) >> 1; if (batch[m] < g) s0 = m + 1; else s1 = m; }
    const int start = s0;
    int e0 = start, e1 = N_NODES;
    while (e0 < e1) { int m = (e0 + e1) >> 1; if (batch[m] < g + 1) e0 = m + 1; else e1 = m; }
    const int end = e0;

    __shared__ __align__(1024) u16 vbuf[2048];   // 64 nodes x 32 e (bf16), 4KB
    __shared__ float posb[192];                  // 64 nodes x 3
    __shared__ __align__(16) float red[4096];    // 4 waves x 32x32 partials

    f32x16 acc;
#pragma unroll
    for (int r = 0; r < 16; r++) acc[r] = 0.0f;

    const int nl0 = w * 16 + hi * 8;             // this half-wave's first local node

    for (int c = start; c < end; c += 64) {
        __syncthreads();                         // prior chunk's readers done
        if (tid < 192) {                         // stage pos[c .. c+64)
            int i = c * 3 + tid;
            posb[tid] = (i < 3 * N_NODES) ? pos[i] : 0.0f;
        }
        {                                        // stage V slice: 64 rows x 64B
            int r = tid >> 2;
            int nn = c + r;
            const u16* gp = V + (size_t)nn * K_DIM + (grp << 5) + ((tid & 3) << 3);
            if (nn < N_NODES)
                __builtin_amdgcn_global_load_lds((gbl_void*)gp,
                                                 (lds_void*)&vbuf[w << 9], 16, 0, 0);
        }
        __syncthreads();                         // drains vmcnt (glds) too

        union { bf16x8 v; u16 u[8]; } A, B;
#pragma unroll
        for (int j = 0; j < 8; j++) {
            int nl = nl0 + j;                    // local node 0..63
            int n = c + nl;
            float ph = posb[nl * 3 + 0] * f0 + posb[nl * 3 + 1] * f1
                     + posb[nl * 3 + 2] * f2;
            float sn, cs;
            __sincosf(ph, &sn, &cs);
            float kd = sgn ? (sn + cs) : (cs - sn);
            bool valid = n < end;
            A.u[j] = valid ? f2bf(kd) : (u16)0;
            B.u[j] = valid ? vbuf[(nl << 5) + de] : (u16)0;
        }
        acc = __builtin_amdgcn_mfma_f32_32x32x16_bf16(A.v, B.v, acc, 0, 0, 0);
    }

    // reduce 4 wave-partials through LDS; C/D map: col=lane&31,
    // row=(reg&3)+8*(reg>>2)+4*(lane>>5)
#pragma unroll
    for (int r = 0; r < 16; r++) {
        int d = (r & 3) + ((r >> 2) << 3) + (hi << 2);
        red[(w << 10) + (d << 5) + de] = acc[r];
    }
    __syncthreads();
    {
        int i4 = tid << 2;
        f32x4 a0 = *reinterpret_cast<const f32x4*>(&red[i4]);
        f32x4 a1 = *reinterpret_cast<const f32x4*>(&red[1024 + i4]);
        f32x4 a2 = *reinterpret_cast<const f32x4*>(&red[2048 + i4]);
        f32x4 a3 = *reinterpret_cast<const f32x4*>(&red[3072 + i4]);
        f32x4 s = (a0 + a1 + a2 + a3) * (1.0f / 512.0f);
        *reinterpret_cast<f32x4*>(&KV[((size_t)(g * 12 + grp) << 10) + i4]) = s;
    }
}

// ---------------------------------------------------------------------------
// attn_mfma: O[n][grp*32+e] = sum_d rope(q)[n][grp][d] * KV[batch[n]][grp][d][e]
// One block per (128-node chunk, grp): 3072 blocks x 256 threads (4 waves).
// VERIFIED round-10.
__global__ __launch_bounds__(256) void attn_mfma(
    u16* __restrict__ Qw, const float* __restrict__ pos,
    const int* __restrict__ batch, const float* __restrict__ freqs,
    const float* __restrict__ KV) {
    const int bid = blockIdx.x;               // 3072 = 256 chunks * 12 groups
    const int xcd = bid & 7, jj = bid >> 3;   // jj 0..383
    const int chunk = (xcd << 5) + jj / 12, grp = jj % 12;
    const int nbase = chunk << 7;

    const int tid = threadIdx.x;
    const int w = tid >> 6, lane = tid & 63;
    const int hi = lane >> 5, de = lane & 31;

    __shared__ float sfreq[48];               // this grp: 16 pairs x 3
    __shared__ __align__(16) float red[4096]; // O tile fp32 [128][32]

    if (tid < 48) sfreq[tid] = freqs[grp * 48 + tid];

    const int node = nbase + (w << 5) + de;
    const float p0 = pos[node * 3 + 0];
    const float p1 = pos[node * 3 + 1];
    const float p2 = pos[node * 3 + 2];
    const int bnode = batch[node];
    const int g0 = batch[nbase + (w << 5)];
    const int g1 = batch[nbase + (w << 5) + 31];

    // raw Q fragment: A layout row = de (node), k = hi*8+j (d within group)
    union { bf16x8 v; u16 u[8]; } qlo, qhi, alo, ahi;
    {
        const u16* qp = Qw + (size_t)node * K_DIM + (grp << 5) + (hi << 3);
        qlo.v = *reinterpret_cast<const bf16x8*>(qp);        // d = hi*8+j
        qhi.v = *reinterpret_cast<const bf16x8*>(qp + 16);   // d = 16+hi*8+j
    }
    __syncthreads();                          // sfreq visible
#pragma unroll
    for (int z = 0; z < 4; z++) {
        const int pl = (hi << 2) + z;                        // pair for lo half
        const float* F  = &sfreq[pl * 3];
        const float* F2 = &sfreq[(8 + pl) * 3];              // pair for hi half
        float sn, cs, sn2, cs2;
        __sincosf(p0 * F[0]  + p1 * F[1]  + p2 * F[2],  &sn,  &cs);
        __sincosf(p0 * F2[0] + p1 * F2[1] + p2 * F2[2], &sn2, &cs2);
        float x1 = bf2f(qlo.u[2 * z]), x2 = bf2f(qlo.u[2 * z + 1]);
        alo.u[2 * z]     = f2bf(x1 * cs - x2 * sn);
        alo.u[2 * z + 1] = f2bf(x1 * sn + x2 * cs);
        float y1 = bf2f(qhi.u[2 * z]), y2 = bf2f(qhi.u[2 * z + 1]);
        ahi.u[2 * z]     = f2bf(y1 * cs2 - y2 * sn2);
        ahi.u[2 * z + 1] = f2bf(y1 * sn2 + y2 * cs2);
    }

    f32x16 oacc;
#pragma unroll
    for (int r = 0; r < 16; r++) oacc[r] = 0.0f;
    for (int g = g0; g <= g1; g++) {
        const bool msk = (bnode == g);
        union { bf16x8 v; u16 u[8]; } ml, mh, bl, bh;
#pragma unroll
        for (int j = 0; j < 8; j++) {
            ml.u[j] = msk ? alo.u[j] : (u16)0;
            mh.u[j] = msk ? ahi.u[j] : (u16)0;
        }
        const float* kvp = KV + (((size_t)(g * 12 + grp)) << 10) + de;
#pragma unroll
        for (int j = 0; j < 8; j++) {                        // B[k=d][col=e=de]
            bl.u[j] = f2bf(kvp[(hi * 8 + j) << 5]);
            bh.u[j] = f2bf(kvp[(16 + hi * 8 + j) << 5]);
        }
        oacc = __builtin_amdgcn_mfma_f32_32x32x16_bf16(ml.v, bl.v, oacc, 0, 0, 0);
        oacc = __builtin_amdgcn_mfma_f32_32x32x16_bf16(mh.v, bh.v, oacc, 0, 0, 0);
    }

    // C/D map: col=lane&31, row=(reg&3)+8*(reg>>2)+4*(lane>>5)
#pragma unroll
    for (int r = 0; r < 16; r++) {
        int rl = (r & 3) + ((r >> 2) << 3) + (hi << 2);
        red[((w << 5) + rl) * 32 + de] = oacc[r];
    }
    __syncthreads();
    {
        const int row = tid >> 1, half = tid & 1;
        union { u16 u[16]; float4 v[2]; } pk;
#pragma unroll
        for (int z = 0; z < 16; z++)
            pk.u[z] = f2bf(red[row * 32 + half * 16 + z]);
        float4* dst = reinterpret_cast<float4*>(
            Qw + (size_t)(nbase + row) * K_DIM + (grp << 5) + (half << 4));
        dst[0] = pk.v[0];
        dst[1] = pk.v[1];
    }
}

// ---------------------------------------------------------------------------
extern "C" void kernel_launch(void* const* d_in, const int* in_sizes, int n_in,
                              void* d_out, int out_size, void* d_ws, size_t ws_size,
                              hipStream_t stream) {
    const float* x     = (const float*)d_in[0];
    const float* pos   = (const float*)d_in[1];
    const int*   batch = (const int*)d_in[2];
    const float* Wq    = (const float*)d_in[3];
    const float* bq    = (const float*)d_in[4];
    const float* Wv    = (const float*)d_in[5];
    const float* bv    = (const float*)d_in[6];
    const float* Wo    = (const float*)d_in[7];
    const float* bo    = (const float*)d_in[8];
    const float* fr    = (const float*)d_in[9];
    float* out = (float*)d_out;

    char* ws = (char*)d_ws;                   // total use ~29.2 MB
    float* KV   = (float*)(ws);               //  3,145,728 B  [g][grp][d][e] fp32
    u16*   WqvT = (u16*)(ws + 3145728);       //    589,824 B
    u16*   WoT  = (u16*)(ws + 3735552);       //    294,912 B
    u16*   Qw   = (u16*)(ws + 4030464);       // 25,165,824 B (Q, then O in-place)
    // d_out (50.3 MB fp32) doubles as scratch until gemm_out overwrites it:
    u16*   Vd   = (u16*)d_out;                // [0, 25.2 MB): V bf16

    prep<<<dim3(432), dim3(256), 0, stream>>>(Wq, Wv, Wo, WqvT, WoT);
    gemm_qv<<<dim3(1536), dim3(256), 0, stream>>>(x, WqvT, bq, bv, Qw, Vd);
    kv_mfma<<<dim3(768), dim3(256), 0, stream>>>(Vd, pos, batch, fr, KV);
    attn_mfma<<<dim3(3072), dim3(256), 0, stream>>>(Qw, pos, batch, fr, KV);
    gemm_out<<<dim3(768), dim3(256), 0, stream>>>(Qw, WoT, bo, out);
}

// Round 8
// 206.429 us; speedup vs baseline: 1.0298x; 1.0298x over previous
//
#include <hip/hip_runtime.h>

// PlatonicConv: linear attention with tetrahedral-group RoPE.
// N=32768 nodes, C=E=384, G=12 groups, H=1, D=32, P=16, 64 graphs (batch sorted).
// I/O fp32; internal bf16 MFMA with fp32 accumulate.
//
// Round 15 (rocprof: gemm_qv SQ_LDS_BANK_CONFLICT=1.77e7 = ~29us stall; the
// fp32 [128][64] A-tile's 256B row stride made the fragment read 16-way
// bank-conflicted -- bank start (q*8)%32 independent of row):
//  - XOR-swizzle the A-tile in 16B units: pc16 = fc16 ^ (row&7). Applied on
//    BOTH sides per rule #21: glds SOURCE column pre-swizzled (LDS dest
//    linear), fragment READ address swizzled. Bit-identical values.
// Pipeline (5 dispatches): prep(W-T only), gemm_qv(fp32-A swz), kv_mfma,
// attn_mfma, gemm_out.

#define N_NODES 32768
#define K_DIM   384
#define P_PAIR  16
#define NUM_GRAPHS 64

typedef unsigned short u16;
typedef __bf16 bf16x8 __attribute__((ext_vector_type(8)));
typedef float  f32x4  __attribute__((ext_vector_type(4)));
typedef float  f32x16 __attribute__((ext_vector_type(16)));
typedef __attribute__((address_space(3))) void       lds_void;
typedef const __attribute__((address_space(1))) void gbl_void;

__device__ __forceinline__ u16 f2bf(float f) {
    unsigned int i = __float_as_uint(f);
    unsigned int r = i + 0x7FFFu + ((i >> 16) & 1u);   // RNE
    return (u16)(r >> 16);
}
__device__ __forceinline__ float bf2f(u16 u) {
    union { unsigned int i; float f; } x;
    x.i = ((unsigned int)u) << 16;
    return x.f;
}

// ---------------------------------------------------------------------------
// prep: W transposes only.  432 blocks = 3 matrices x 144 32x32 tiles:
// WqvT[n][k]=[Wq|Wv][k][n], WoT[n][k]=Wo[k][n].
__global__ void prep(const float* __restrict__ Wq, const float* __restrict__ Wv,
                     const float* __restrict__ Wo,
                     u16* __restrict__ WqvT, u16* __restrict__ WoT) {
    __shared__ float ld[32][33];
    const int tb  = blockIdx.x;
    const int mat = tb / 144;                    // 0: Wq, 1: Wv, 2: Wo
    const int tl  = tb % 144;
    const int tr  = tl / 12, tc = tl % 12;       // src tile row (k), col (n)
    const float* src = (mat == 0) ? Wq : (mat == 1) ? Wv : Wo;
    u16* dst = (mat == 2) ? WoT : WqvT;
    const int n_off = (mat == 1) ? 384 : 0;

    const int t = threadIdx.x;
    const int c = t & 31, r = t >> 5;            // 8 rows per pass
#pragma unroll
    for (int i = 0; i < 4; i++) {
        int r0 = r + (i << 3);
        ld[r0][c] = src[(tr * 32 + r0) * 384 + tc * 32 + c];
    }
    __syncthreads();
    const int ck = t & 31;
#pragma unroll
    for (int i = 0; i < 4; i++) {
        int cn = r + (i << 3);
        dst[(size_t)(n_off + tc * 32 + cn) * 384 + tr * 32 + ck] = f2bf(ld[ck][cn]);
    }
}

// ---------------------------------------------------------------------------
// Shared GEMM core (bf16 A+B, used by gemm_out): 128x128 tile, BK=64 as four
// 128x32 sub-tiles [A0|A1|B0|B1], staged via glds w16.  ROUND-11 VERIFIED.
#define GEMM_CORE(A_PTR, B_PTR)                                                  \
    __shared__ __align__(1024) u16 T[16384];                                     \
    const int tid = threadIdx.x;                                                 \
    const int w = tid >> 6, lane = tid & 63;                                     \
    const int wr = (w >> 1) << 6, wc = (w & 1) << 6;                             \
    const int lm = lane & 15, q = lane >> 4;                                     \
    const int srow = lane >> 2, sc8 = (lane & 3) << 3;                           \
    f32x4 acc[4][4];                                                             \
    _Pragma("unroll") for (int i = 0; i < 4; i++)                                \
    _Pragma("unroll") for (int j = 0; j < 4; j++)                                \
    _Pragma("unroll") for (int r = 0; r < 4; r++) acc[i][j][r] = 0.0f;           \
    for (int k0 = 0; k0 < K_DIM; k0 += 64) {                                     \
        __syncthreads();                                                         \
        _Pragma("unroll")                                                        \
        for (int s = w; s < 32; s += 4) {                                        \
            int row  = ((s & 7) << 4) + srow;                                    \
            int half = (s >> 3) & 1;                                             \
            const u16* gp = ((s >> 4) ? (B_PTR) + (size_t)(n0 + row) * K_DIM     \
                                      : (A_PTR) + (size_t)(m0 + row) * K_DIM)    \
                            + k0 + (half << 5) + sc8;                            \
            __builtin_amdgcn_global_load_lds((gbl_void*)gp,                      \
                                             (lds_void*)&T[s << 9], 16, 0, 0);   \
        }                                                                        \
        __syncthreads();                                                         \
        _Pragma("unroll")                                                        \
        for (int h = 0; h < 2; h++) {                                            \
            bf16x8 af[4], bfr[4];                                                \
            _Pragma("unroll") for (int i = 0; i < 4; i++) {                      \
                af[i]  = *reinterpret_cast<const bf16x8*>(                       \
                    &T[(h << 12) + (wr + i * 16 + lm) * 32 + q * 8]);            \
                bfr[i] = *reinterpret_cast<const bf16x8*>(                       \
                    &T[8192 + (h << 12) + (wc + i * 16 + lm) * 32 + q * 8]);     \
            }                                                                    \
            _Pragma("unroll") for (int i = 0; i < 4; i++)                        \
            _Pragma("unroll") for (int j = 0; j < 4; j++)                        \
                acc[i][j] = __builtin_amdgcn_mfma_f32_16x16x32_bf16(             \
                    af[i], bfr[j], acc[i][j], 0, 0, 0);                          \
        }                                                                        \
    }

// ---------------------------------------------------------------------------
// [Q|V] = bf16(x) @ [Wq|Wv]^T + [bq|bv], fp32 x staged directly.
// A-region: 32KB fp32, XOR-swizzled in 16B units: physical pc16 = fc16^(row&7).
//   stage: dest linear (row=4s+(l>>4), pc16=l&15) <- global col fc16=(l&15)^(row&7)
//   read : logical unit u=h*8+q*2+{0,1} at physical (u^(row&7))<<2
// -> fragment-read bank start varies with lm&7: 2 lanes/bank-group (free).
// B-region: bf16 [2][128][32] at byte 32768 (verified layout).
// A fragment: two swizzled ds_read_b128 + 4 v_cvt_pk_bf16_f32 (RNE == f2bf).
__global__ __launch_bounds__(256) void gemm_qv(
    const float* __restrict__ X, const u16* __restrict__ Bt,
    const float* __restrict__ bq, const float* __restrict__ bv,
    u16* __restrict__ Qw, u16* __restrict__ Vd) {
    const int b = blockIdx.x;                 // 1536 blocks
    const int xcd = b & 7, jj = b >> 3;       // jj 0..191
    const int by = xcd * 32 + jj / 6, bx = jj % 6;
    const int m0 = by << 7, n0 = bx << 7;

    __shared__ __align__(1024) u16 T[24576];  // [0,32KB): A fp32; [32,48KB): B bf16
    float* Af = reinterpret_cast<float*>(T);
    const int tid = threadIdx.x;
    const int w = tid >> 6, lane = tid & 63;
    const int wr = (w >> 1) << 6, wc = (w & 1) << 6;
    const int lm = lane & 15, q = lane >> 4;
    const int srow = lane >> 2, sc8 = (lane & 3) << 3;
    const int arow = lane >> 4;               // A-staging: row within 4-row segment

    f32x4 acc[4][4];
#pragma unroll
    for (int i = 0; i < 4; i++)
#pragma unroll
    for (int j = 0; j < 4; j++)
#pragma unroll
    for (int r = 0; r < 4; r++) acc[i][j][r] = 0.0f;

    for (int k0 = 0; k0 < K_DIM; k0 += 64) {
        __syncthreads();
        // stage A (fp32 x): 32 segments x 1024B; source col pre-swizzled
#pragma unroll
        for (int s = w; s < 32; s += 4) {
            const int row  = (s << 2) + arow;
            const int fc16 = (lane & 15) ^ (row & 7);
            const float* gp = X + (size_t)(m0 + row) * K_DIM + k0 + (fc16 << 2);
            __builtin_amdgcn_global_load_lds((gbl_void*)gp,
                                             (lds_void*)&Af[s << 8], 16, 0, 0);
        }
        // stage B (bf16 WqvT): 16 segments x 1024B (verified layout)
#pragma unroll
        for (int s = w; s < 16; s += 4) {
            int row  = ((s & 7) << 4) + srow;
            int half = (s >> 3) & 1;
            const u16* gp = Bt + (size_t)(n0 + row) * K_DIM + k0 + (half << 5) + sc8;
            __builtin_amdgcn_global_load_lds((gbl_void*)gp,
                                             (lds_void*)&T[16384 + (s << 9)], 16, 0, 0);
        }
        __syncthreads();
#pragma unroll
        for (int h = 0; h < 2; h++) {
            bf16x8 af[4], bfr[4];
#pragma unroll
            for (int i = 0; i < 4; i++) {
                const int row = wr + i * 16 + lm;
                const int ub  = (h << 3) + (q << 1);         // logical 16B unit
                const int u0  = (ub ^ (row & 7)) << 2;
                const int u1  = ((ub + 1) ^ (row & 7)) << 2;
                f32x4 a0 = *reinterpret_cast<const f32x4*>(&Af[row * 64 + u0]);
                f32x4 a1 = *reinterpret_cast<const f32x4*>(&Af[row * 64 + u1]);
                union { bf16x8 v; unsigned int u[4]; } pk;
                asm("v_cvt_pk_bf16_f32 %0, %1, %2" : "=v"(pk.u[0]) : "v"(a0[0]), "v"(a0[1]));
                asm("v_cvt_pk_bf16_f32 %0, %1, %2" : "=v"(pk.u[1]) : "v"(a0[2]), "v"(a0[3]));
                asm("v_cvt_pk_bf16_f32 %0, %1, %2" : "=v"(pk.u[2]) : "v"(a1[0]), "v"(a1[1]));
                asm("v_cvt_pk_bf16_f32 %0, %1, %2" : "=v"(pk.u[3]) : "v"(a1[2]), "v"(a1[3]));
                af[i] = pk.v;
                bfr[i] = *reinterpret_cast<const bf16x8*>(
                    &T[16384 + (h << 12) + (wc + i * 16 + lm) * 32 + q * 8]);
            }
#pragma unroll
            for (int i = 0; i < 4; i++)
#pragma unroll
            for (int j = 0; j < 4; j++)
                acc[i][j] = __builtin_amdgcn_mfma_f32_16x16x32_bf16(
                    af[i], bfr[j], acc[i][j], 0, 0, 0);
        }
    }
    // C/D layout: col = lane&15, row = (lane>>4)*4 + r  [HW-confirmed]
    u16* Cq = (n0 < 384) ? Qw : Vd;
    const float* bias = (n0 < 384) ? bq : bv;
    const int coff = (n0 < 384) ? 0 : 384;
#pragma unroll
    for (int j = 0; j < 4; j++) {
        int gc = n0 + wc + j * 16 + lm - coff;
        float bs = bias[gc];
#pragma unroll
        for (int i = 0; i < 4; i++) {
            int gr = m0 + wr + i * 16 + q * 4;
#pragma unroll
            for (int r = 0; r < 4; r++)
                Cq[(size_t)(gr + r) * 384 + gc] = f2bf(acc[i][j][r] + bs);
        }
    }
}

// ---------------------------------------------------------------------------
// out = O @ Wo^T + bo (fp32 out).  O = attn output, in-place over Qw.
__global__ __launch_bounds__(256) void gemm_out(
    const u16* __restrict__ A, const u16* __restrict__ Bt,
    const float* __restrict__ bias, float* __restrict__ Cmat) {
    const int b = blockIdx.x;                 // 768 blocks
    const int xcd = b & 7, jj = b >> 3;       // jj 0..95
    const int by = xcd * 32 + jj / 3, bx = jj % 3;
    const int m0 = by << 7, n0 = bx << 7;
    GEMM_CORE(A, Bt)
#pragma unroll
    for (int j = 0; j < 4; j++) {
        int gc = n0 + wc + j * 16 + lm;
        float bs = bias[gc];
#pragma unroll
        for (int i = 0; i < 4; i++) {
            int gr = m0 + wr + i * 16 + q * 4;
#pragma unroll
            for (int r = 0; r < 4; r++)
                Cmat[(size_t)(gr + r) * 384 + gc] = acc[i][j][r] + bs;
        }
    }
}

// ---------------------------------------------------------------------------
// kv_mfma: KV[g][grp][d][e] = (1/512) sum_{n in graph g} k[n][grp][d] v[n][grp][e]
// One block per (g, grp): 768 blocks x 256 threads (4 waves), 32x32xK MFMA
// over the graph's nodes.  k = rope(ones).  fp32 flat [d][e] output. VERIFIED.
__global__ __launch_bounds__(256) void kv_mfma(
    const u16* __restrict__ V, const float* __restrict__ pos,
    const int* __restrict__ batch, const float* __restrict__ freqs,
    float* __restrict__ KV) {
    const int bid = blockIdx.x;               // 768 = 64 graphs * 12 groups
    const int xcd = bid & 7, jj = bid >> 3;   // jj 0..95
    const int g = (xcd << 3) + jj / 12, grp = jj % 12;

    const int tid = threadIdx.x;
    const int w = tid >> 6, lane = tid & 63;
    const int hi = lane >> 5, de = lane & 31; // A-row d == B-col e == de
    const int p = de >> 1, sgn = de & 1;

    const float f0 = freqs[(grp * P_PAIR + p) * 3 + 0];
    const float f1 = freqs[(grp * P_PAIR + p) * 3 + 1];
    const float f2 = freqs[(grp * P_PAIR + p) * 3 + 2];

    // segment bounds (uniform across block)
    int s0 = 0, s1 = N_NODES;
    while (s0 < s1) { int m = (s0 + s1) >> 1; if (batch[m] < g) s0 = m + 1; else s1 = m; }
    const int start = s0;
    int e0 = start, e1 = N_NODES;
    while (e0 < e1) { int m = (e0 + e1) >> 1; if (batch[m] < g + 1) e0 = m + 1; else e1 = m; }
    const int end = e0;

    __shared__ __align__(1024) u16 vbuf[2048];   // 64 nodes x 32 e (bf16), 4KB
    __shared__ float posb[192];                  // 64 nodes x 3
    __shared__ __align__(16) float red[4096];    // 4 waves x 32x32 partials

    f32x16 acc;
#pragma unroll
    for (int r = 0; r < 16; r++) acc[r] = 0.0f;

    const int nl0 = w * 16 + hi * 8;             // this half-wave's first local node

    for (int c = start; c < end; c += 64) {
        __syncthreads();                         // prior chunk's readers done
        if (tid < 192) {                         // stage pos[c .. c+64)
            int i = c * 3 + tid;
            posb[tid] = (i < 3 * N_NODES) ? pos[i] : 0.0f;
        }
        {                                        // stage V slice: 64 rows x 64B
            int r = tid >> 2;
            int nn = c + r;
            const u16* gp = V + (size_t)nn * K_DIM + (grp << 5) + ((tid & 3) << 3);
            if (nn < N_NODES)
                __builtin_amdgcn_global_load_lds((gbl_void*)gp,
                                                 (lds_void*)&vbuf[w << 9], 16, 0, 0);
        }
        __syncthreads();                         // drains vmcnt (glds) too

        union { bf16x8 v; u16 u[8]; } A, B;
#pragma unroll
        for (int j = 0; j < 8; j++) {
            int nl = nl0 + j;                    // local node 0..63
            int n = c + nl;
            float ph = posb[nl * 3 + 0] * f0 + posb[nl * 3 + 1] * f1
                     + posb[nl * 3 + 2] * f2;
            float sn, cs;
            __sincosf(ph, &sn, &cs);
            float kd = sgn ? (sn + cs) : (cs - sn);
            bool valid = n < end;
            A.u[j] = valid ? f2bf(kd) : (u16)0;
            B.u[j] = valid ? vbuf[(nl << 5) + de] : (u16)0;
        }
        acc = __builtin_amdgcn_mfma_f32_32x32x16_bf16(A.v, B.v, acc, 0, 0, 0);
    }

    // reduce 4 wave-partials through LDS; C/D map: col=lane&31,
    // row=(reg&3)+8*(reg>>2)+4*(lane>>5)
#pragma unroll
    for (int r = 0; r < 16; r++) {
        int d = (r & 3) + ((r >> 2) << 3) + (hi << 2);
        red[(w << 10) + (d << 5) + de] = acc[r];
    }
    __syncthreads();
    {
        int i4 = tid << 2;
        f32x4 a0 = *reinterpret_cast<const f32x4*>(&red[i4]);
        f32x4 a1 = *reinterpret_cast<const f32x4*>(&red[1024 + i4]);
        f32x4 a2 = *reinterpret_cast<const f32x4*>(&red[2048 + i4]);
        f32x4 a3 = *reinterpret_cast<const f32x4*>(&red[3072 + i4]);
        f32x4 s = (a0 + a1 + a2 + a3) * (1.0f / 512.0f);
        *reinterpret_cast<f32x4*>(&KV[((size_t)(g * 12 + grp) << 10) + i4]) = s;
    }
}

// ---------------------------------------------------------------------------
// attn_mfma: O[n][grp*32+e] = sum_d rope(q)[n][grp][d] * KV[batch[n]][grp][d][e]
// One block per (128-node chunk, grp): 3072 blocks x 256 threads (4 waves).
// VERIFIED round-10.
__global__ __launch_bounds__(256) void attn_mfma(
    u16* __restrict__ Qw, const float* __restrict__ pos,
    const int* __restrict__ batch, const float* __restrict__ freqs,
    const float* __restrict__ KV) {
    const int bid = blockIdx.x;               // 3072 = 256 chunks * 12 groups
    const int xcd = bid & 7, jj = bid >> 3;   // jj 0..383
    const int chunk = (xcd << 5) + jj / 12, grp = jj % 12;
    const int nbase = chunk << 7;

    const int tid = threadIdx.x;
    const int w = tid >> 6, lane = tid & 63;
    const int hi = lane >> 5, de = lane & 31;

    __shared__ float sfreq[48];               // this grp: 16 pairs x 3
    __shared__ __align__(16) float red[4096]; // O tile fp32 [128][32]

    if (tid < 48) sfreq[tid] = freqs[grp * 48 + tid];

    const int node = nbase + (w << 5) + de;
    const float p0 = pos[node * 3 + 0];
    const float p1 = pos[node * 3 + 1];
    const float p2 = pos[node * 3 + 2];
    const int bnode = batch[node];
    const int g0 = batch[nbase + (w << 5)];
    const int g1 = batch[nbase + (w << 5) + 31];

    // raw Q fragment: A layout row = de (node), k = hi*8+j (d within group)
    union { bf16x8 v; u16 u[8]; } qlo, qhi, alo, ahi;
    {
        const u16* qp = Qw + (size_t)node * K_DIM + (grp << 5) + (hi << 3);
        qlo.v = *reinterpret_cast<const bf16x8*>(qp);        // d = hi*8+j
        qhi.v = *reinterpret_cast<const bf16x8*>(qp + 16);   // d = 16+hi*8+j
    }
    __syncthreads();                          // sfreq visible
#pragma unroll
    for (int z = 0; z < 4; z++) {
        const int pl = (hi << 2) + z;                        // pair for lo half
        const float* F  = &sfreq[pl * 3];
        const float* F2 = &sfreq[(8 + pl) * 3];              // pair for hi half
        float sn, cs, sn2, cs2;
        __sincosf(p0 * F[0]  + p1 * F[1]  + p2 * F[2],  &sn,  &cs);
        __sincosf(p0 * F2[0] + p1 * F2[1] + p2 * F2[2], &sn2, &cs2);
        float x1 = bf2f(qlo.u[2 * z]), x2 = bf2f(qlo.u[2 * z + 1]);
        alo.u[2 * z]     = f2bf(x1 * cs - x2 * sn);
        alo.u[2 * z + 1] = f2bf(x1 * sn + x2 * cs);
        float y1 = bf2f(qhi.u[2 * z]), y2 = bf2f(qhi.u[2 * z + 1]);
        ahi.u[2 * z]     = f2bf(y1 * cs2 - y2 * sn2);
        ahi.u[2 * z + 1] = f2bf(y1 * sn2 + y2 * cs2);
    }

    f32x16 oacc;
#pragma unroll
    for (int r = 0; r < 16; r++) oacc[r] = 0.0f;
    for (int g = g0; g <= g1; g++) {
        const bool msk = (bnode == g);
        union { bf16x8 v; u16 u[8]; } ml, mh, bl, bh;
#pragma unroll
        for (int j = 0; j < 8; j++) {
            ml.u[j] = msk ? alo.u[j] : (u16)0;
            mh.u[j] = msk ? ahi.u[j] : (u16)0;
        }
        const float* kvp = KV + (((size_t)(g * 12 + grp)) << 10) + de;
#pragma unroll
        for (int j = 0; j < 8; j++) {                        // B[k=d][col=e=de]
            bl.u[j] = f2bf(kvp[(hi * 8 + j) << 5]);
            bh.u[j] = f2bf(kvp[(16 + hi * 8 + j) << 5]);
        }
        oacc = __builtin_amdgcn_mfma_f32_32x32x16_bf16(ml.v, bl.v, oacc, 0, 0, 0);
        oacc = __builtin_amdgcn_mfma_f32_32x32x16_bf16(mh.v, bh.v, oacc, 0, 0, 0);
    }

    // C/D map: col=lane&31, row=(reg&3)+8*(reg>>2)+4*(lane>>5)
#pragma unroll
    for (int r = 0; r < 16; r++) {
        int rl = (r & 3) + ((r >> 2) << 3) + (hi << 2);
        red[((w << 5) + rl) * 32 + de] = oacc[r];
    }
    __syncthreads();
    {
        const int row = tid >> 1, half = tid & 1;
        union { u16 u[16]; float4 v[2]; } pk;
#pragma unroll
        for (int z = 0; z < 16; z++)
            pk.u[z] = f2bf(red[row * 32 + half * 16 + z]);
        float4* dst = reinterpret_cast<float4*>(
            Qw + (size_t)(nbase + row) * K_DIM + (grp << 5) + (half << 4));
        dst[0] = pk.v[0];
        dst[1] = pk.v[1];
    }
}

// ---------------------------------------------------------------------------
extern "C" void kernel_launch(void* const* d_in, const int* in_sizes, int n_in,
                              void* d_out, int out_size, void* d_ws, size_t ws_size,
                              hipStream_t stream) {
    const float* x     = (const float*)d_in[0];
    const float* pos   = (const float*)d_in[1];
    const int*   batch = (const int*)d_in[2];
    const float* Wq    = (const float*)d_in[3];
    const float* bq    = (const float*)d_in[4];
    const float* Wv    = (const float*)d_in[5];
    const float* bv    = (const float*)d_in[6];
    const float* Wo    = (const float*)d_in[7];
    const float* bo    = (const float*)d_in[8];
    const float* fr    = (const float*)d_in[9];
    float* out = (float*)d_out;

    char* ws = (char*)d_ws;                   // total use ~29.2 MB
    float* KV   = (float*)(ws);               //  3,145,728 B  [g][grp][d][e] fp32
    u16*   WqvT = (u16*)(ws + 3145728);       //    589,824 B
    u16*   WoT  = (u16*)(ws + 3735552);       //    294,912 B
    u16*   Qw   = (u16*)(ws + 4030464);       // 25,165,824 B (Q, then O in-place)
    // d_out (50.3 MB fp32) doubles as scratch until gemm_out overwrites it:
    u16*   Vd   = (u16*)d_out;                // [0, 25.2 MB): V bf16

    prep<<<dim3(432), dim3(256), 0, stream>>>(Wq, Wv, Wo, WqvT, WoT);
    gemm_qv<<<dim3(1536), dim3(256), 0, stream>>>(x, WqvT, bq, bv, Qw, Vd);
    kv_mfma<<<dim3(768), dim3(256), 0, stream>>>(Vd, pos, batch, fr, KV);
    attn_mfma<<<dim3(3072), dim3(256), 0, stream>>>(Qw, pos, batch, fr, KV);
    gemm_out<<<dim3(768), dim3(256), 0, stream>>>(Qw, WoT, bo, out);
}

// Round 9
// 195.433 us; speedup vs baseline: 1.0877x; 1.0563x over previous
//
#include <hip/hip_runtime.h>

// PlatonicConv: linear attention with tetrahedral-group RoPE.
// N=32768 nodes, C=E=384, G=12 groups, H=1, D=32, P=16, 64 graphs (batch sorted).
// I/O fp32; internal bf16 MFMA with fp32 accumulate.
//
// Round 16: fp32-direct gemm_qv shelved (48KB LDS -> 3 blocks/CU, 2x FETCH;
// 206 vs round-4's 195). Reverted to round-4 bf16-xb pipeline, PLUS the
// lesson it taught: every [128][32] bf16 tile read is 4-way bank-conflicted
// (bank-group = (row&1)*4+q). Fix: unit-XOR swizzle pu = q ^ ((row>>1)&3),
// both sides (rule #21): glds SOURCE unit pre-swizzled, LDS dest linear,
// fragment READ swizzled. Placement-only -> bit-identical results.
// Pipeline (5 dispatches): prep, gemm_qv, kv_mfma, attn_mfma, gemm_out.

#define N_NODES 32768
#define K_DIM   384
#define P_PAIR  16
#define NUM_GRAPHS 64

typedef unsigned short u16;
typedef __bf16 bf16x8 __attribute__((ext_vector_type(8)));
typedef float  f32x4  __attribute__((ext_vector_type(4)));
typedef float  f32x16 __attribute__((ext_vector_type(16)));
typedef __attribute__((address_space(3))) void       lds_void;
typedef const __attribute__((address_space(1))) void gbl_void;

__device__ __forceinline__ u16 f2bf(float f) {
    unsigned int i = __float_as_uint(f);
    unsigned int r = i + 0x7FFFu + ((i >> 16) & 1u);   // RNE
    return (u16)(r >> 16);
}
__device__ __forceinline__ float bf2f(u16 u) {
    union { unsigned int i; float f; } x;
    x.i = ((unsigned int)u) << 16;
    return x.f;
}

// ---------------------------------------------------------------------------
// prep: xb = bf16(x) (vectorized x8, blocks 0..6143); W transposes via
// LDS-tiled 32x32 (blocks 6144..6575): WqvT[n][k]=[Wq|Wv][k][n], WoT[n][k]=Wo[k][n].
__global__ void prep(const float* __restrict__ x,
                     const float* __restrict__ Wq, const float* __restrict__ Wv,
                     const float* __restrict__ Wo,
                     u16* __restrict__ xb, u16* __restrict__ WqvT,
                     u16* __restrict__ WoT) {
    int b = blockIdx.x;
    if (b < 6144) {                              // 6144*256*8 = 12,582,912 = N*384
        int i = (b * 256 + threadIdx.x) * 8;
        float4 a0 = *reinterpret_cast<const float4*>(x + i);
        float4 a1 = *reinterpret_cast<const float4*>(x + i + 4);
        union { u16 u[8]; float4 v; } pk;
        pk.u[0] = f2bf(a0.x); pk.u[1] = f2bf(a0.y);
        pk.u[2] = f2bf(a0.z); pk.u[3] = f2bf(a0.w);
        pk.u[4] = f2bf(a1.x); pk.u[5] = f2bf(a1.y);
        pk.u[6] = f2bf(a1.z); pk.u[7] = f2bf(a1.w);
        *reinterpret_cast<float4*>(xb + i) = pk.v;
        return;
    }
    // tiled transpose: 432 blocks = 3 matrices x 144 (12x12) 32x32 tiles
    __shared__ float ld[32][33];
    const int tb  = b - 6144;
    const int mat = tb / 144;                    // 0: Wq, 1: Wv, 2: Wo
    const int tl  = tb % 144;
    const int tr  = tl / 12, tc = tl % 12;       // src tile row (k), col (n)
    const float* src = (mat == 0) ? Wq : (mat == 1) ? Wv : Wo;
    u16* dst = (mat == 2) ? WoT : WqvT;
    const int n_off = (mat == 1) ? 384 : 0;

    const int t = threadIdx.x;
    const int c = t & 31, r = t >> 5;            // 8 rows per pass
#pragma unroll
    for (int i = 0; i < 4; i++) {
        int r0 = r + (i << 3);
        ld[r0][c] = src[(tr * 32 + r0) * 384 + tc * 32 + c];
    }
    __syncthreads();
    const int ck = t & 31;
#pragma unroll
    for (int i = 0; i < 4; i++) {
        int cn = r + (i << 3);
        dst[(size_t)(n_off + tc * 32 + cn) * 384 + tr * 32 + ck] = f2bf(ld[ck][cn]);
    }
}

// ---------------------------------------------------------------------------
// Shared GEMM core: 128x128 tile, BK=64 as four 128x32 sub-tiles [A0|A1|B0|B1],
// each 4096 u16, staged via glds w16 (8 segments x 1024B per sub-tile).
// Unit-XOR swizzle per sub-tile: a row's four 16B units are stored physically
// at pu = lu ^ ((row>>1)&3).  Stage: LDS dest linear, SOURCE unit pre-swizzled
// (lu = (lane&3) ^ ((row>>1)&3)).  Read: logical unit q at physical
// q ^ ((row>>1)&3).  8-lane read batches cover all 8 bank groups ->
// conflict-free.  4 waves 2x2, 4x4 16x16x32 MFMA, two k-halves per K-step.
#define GEMM_CORE(A_PTR, B_PTR)                                                  \
    __shared__ __align__(1024) u16 T[16384];                                     \
    const int tid = threadIdx.x;                                                 \
    const int w = tid >> 6, lane = tid & 63;                                     \
    const int wr = (w >> 1) << 6, wc = (w & 1) << 6;                             \
    const int lm = lane & 15, q = lane >> 4;                                     \
    const int srow = lane >> 2, cu = lane & 3;                                   \
    f32x4 acc[4][4];                                                             \
    _Pragma("unroll") for (int i = 0; i < 4; i++)                                \
    _Pragma("unroll") for (int j = 0; j < 4; j++)                                \
    _Pragma("unroll") for (int r = 0; r < 4; r++) acc[i][j][r] = 0.0f;           \
    for (int k0 = 0; k0 < K_DIM; k0 += 64) {                                     \
        __syncthreads();                                                         \
        _Pragma("unroll")                                                        \
        for (int s = w; s < 32; s += 4) {                                        \
            int row  = ((s & 7) << 4) + srow;                                    \
            int half = (s >> 3) & 1;                                             \
            int lu   = cu ^ ((row >> 1) & 3);                                    \
            const u16* gp = ((s >> 4) ? (B_PTR) + (size_t)(n0 + row) * K_DIM     \
                                      : (A_PTR) + (size_t)(m0 + row) * K_DIM)    \
                            + k0 + (half << 5) + (lu << 3);                      \
            __builtin_amdgcn_global_load_lds((gbl_void*)gp,                      \
                                             (lds_void*)&T[s << 9], 16, 0, 0);   \
        }                                                                        \
        __syncthreads();                                                         \
        _Pragma("unroll")                                                        \
        for (int h = 0; h < 2; h++) {                                            \
            bf16x8 af[4], bfr[4];                                                \
            _Pragma("unroll") for (int i = 0; i < 4; i++) {                      \
                const int ra = wr + i * 16 + lm;                                 \
                const int rb = wc + i * 16 + lm;                                 \
                af[i]  = *reinterpret_cast<const bf16x8*>(                       \
                    &T[(h << 12) + ra * 32 + ((q ^ ((ra >> 1) & 3)) << 3)]);     \
                bfr[i] = *reinterpret_cast<const bf16x8*>(                       \
                    &T[8192 + (h << 12) + rb * 32 + ((q ^ ((rb >> 1) & 3)) << 3)]); \
            }                                                                    \
            _Pragma("unroll") for (int i = 0; i < 4; i++)                        \
            _Pragma("unroll") for (int j = 0; j < 4; j++)                        \
                acc[i][j] = __builtin_amdgcn_mfma_f32_16x16x32_bf16(             \
                    af[i], bfr[j], acc[i][j], 0, 0, 0);                          \
        }                                                                        \
    }

// ---------------------------------------------------------------------------
// [Q|V] = xb @ [Wq|Wv]^T + [bq|bv].  Swizzle: XCD owns 32 row-tiles, bx fastest.
__global__ __launch_bounds__(256) void gemm_qv(
    const u16* __restrict__ A, const u16* __restrict__ Bt,
    const float* __restrict__ bq, const float* __restrict__ bv,
    u16* __restrict__ Qw, u16* __restrict__ Vd) {
    const int b = blockIdx.x;                 // 1536 blocks
    const int xcd = b & 7, jj = b >> 3;       // jj 0..191
    const int by = xcd * 32 + jj / 6, bx = jj % 6;
    const int m0 = by << 7, n0 = bx << 7;
    GEMM_CORE(A, Bt)
    // C/D layout: col = lane&15, row = (lane>>4)*4 + r  [HW-confirmed]
    u16* Cq = (n0 < 384) ? Qw : Vd;
    const float* bias = (n0 < 384) ? bq : bv;
    const int coff = (n0 < 384) ? 0 : 384;
#pragma unroll
    for (int j = 0; j < 4; j++) {
        int gc = n0 + wc + j * 16 + lm - coff;
        float bs = bias[gc];
#pragma unroll
        for (int i = 0; i < 4; i++) {
            int gr = m0 + wr + i * 16 + q * 4;
#pragma unroll
            for (int r = 0; r < 4; r++)
                Cq[(size_t)(gr + r) * 384 + gc] = f2bf(acc[i][j][r] + bs);
        }
    }
}

// ---------------------------------------------------------------------------
// out = O @ Wo^T + bo (fp32 out).  O = attn output, in-place over Qw.
__global__ __launch_bounds__(256) void gemm_out(
    const u16* __restrict__ A, const u16* __restrict__ Bt,
    const float* __restrict__ bias, float* __restrict__ Cmat) {
    const int b = blockIdx.x;                 // 768 blocks
    const int xcd = b & 7, jj = b >> 3;       // jj 0..95
    const int by = xcd * 32 + jj / 3, bx = jj % 3;
    const int m0 = by << 7, n0 = bx << 7;
    GEMM_CORE(A, Bt)
#pragma unroll
    for (int j = 0; j < 4; j++) {
        int gc = n0 + wc + j * 16 + lm;
        float bs = bias[gc];
#pragma unroll
        for (int i = 0; i < 4; i++) {
            int gr = m0 + wr + i * 16 + q * 4;
#pragma unroll
            for (int r = 0; r < 4; r++)
                Cmat[(size_t)(gr + r) * 384 + gc] = acc[i][j][r] + bs;
        }
    }
}

// ---------------------------------------------------------------------------
// kv_mfma: KV[g][grp][d][e] = (1/512) sum_{n in graph g} k[n][grp][d] v[n][grp][e]
// One block per (g, grp): 768 blocks x 256 threads (4 waves), 32x32xK MFMA
// over the graph's nodes.  k = rope(ones).  fp32 flat [d][e] output. VERIFIED.
__global__ __launch_bounds__(256) void kv_mfma(
    const u16* __restrict__ V, const float* __restrict__ pos,
    const int* __restrict__ batch, const float* __restrict__ freqs,
    float* __restrict__ KV) {
    const int bid = blockIdx.x;               // 768 = 64 graphs * 12 groups
    const int xcd = bid & 7, jj = bid >> 3;   // jj 0..95
    const int g = (xcd << 3) + jj / 12, grp = jj % 12;

    const int tid = threadIdx.x;
    const int w = tid >> 6, lane = tid & 63;
    const int hi = lane >> 5, de = lane & 31; // A-row d == B-col e == de
    const int p = de >> 1, sgn = de & 1;

    const float f0 = freqs[(grp * P_PAIR + p) * 3 + 0];
    const float f1 = freqs[(grp * P_PAIR + p) * 3 + 1];
    const float f2 = freqs[(grp * P_PAIR + p) * 3 + 2];

    // segment bounds (uniform across block)
    int s0 = 0, s1 = N_NODES;
    while (s0 < s1) { int m = (s0 + s1) >> 1; if (batch[m] < g) s0 = m + 1; else s1 = m; }
    const int start = s0;
    int e0 = start, e1 = N_NODES;
    while (e0 < e1) { int m = (e0 + e1) >> 1; if (batch[m] < g + 1) e0 = m + 1; else e1 = m; }
    const int end = e0;

    __shared__ __align__(1024) u16 vbuf[2048];   // 64 nodes x 32 e (bf16), 4KB
    __shared__ float posb[192];                  // 64 nodes x 3
    __shared__ __align__(16) float red[4096];    // 4 waves x 32x32 partials

    f32x16 acc;
#pragma unroll
    for (int r = 0; r < 16; r++) acc[r] = 0.0f;

    const int nl0 = w * 16 + hi * 8;             // this half-wave's first local node

    for (int c = start; c < end; c += 64) {
        __syncthreads();                         // prior chunk's readers done
        if (tid < 192) {                         // stage pos[c .. c+64)
            int i = c * 3 + tid;
            posb[tid] = (i < 3 * N_NODES) ? pos[i] : 0.0f;
        }
        {                                        // stage V slice: 64 rows x 64B
            int r = tid >> 2;
            int nn = c + r;
            const u16* gp = V + (size_t)nn * K_DIM + (grp << 5) + ((tid & 3) << 3);
            if (nn < N_NODES)
                __builtin_amdgcn_global_load_lds((gbl_void*)gp,
                                                 (lds_void*)&vbuf[w << 9], 16, 0, 0);
        }
        __syncthreads();                         // drains vmcnt (glds) too

        union { bf16x8 v; u16 u[8]; } A, B;
#pragma unroll
        for (int j = 0; j < 8; j++) {
            int nl = nl0 + j;                    // local node 0..63
            int n = c + nl;
            float ph = posb[nl * 3 + 0] * f0 + posb[nl * 3 + 1] * f1
                     + posb[nl * 3 + 2] * f2;
            float sn, cs;
            __sincosf(ph, &sn, &cs);
            float kd = sgn ? (sn + cs) : (cs - sn);
            bool valid = n < end;
            A.u[j] = valid ? f2bf(kd) : (u16)0;
            B.u[j] = valid ? vbuf[(nl << 5) + de] : (u16)0;
        }
        acc = __builtin_amdgcn_mfma_f32_32x32x16_bf16(A.v, B.v, acc, 0, 0, 0);
    }

    // reduce 4 wave-partials through LDS; C/D map: col=lane&31,
    // row=(reg&3)+8*(reg>>2)+4*(lane>>5)
#pragma unroll
    for (int r = 0; r < 16; r++) {
        int d = (r & 3) + ((r >> 2) << 3) + (hi << 2);
        red[(w << 10) + (d << 5) + de] = acc[r];
    }
    __syncthreads();
    {
        int i4 = tid << 2;
        f32x4 a0 = *reinterpret_cast<const f32x4*>(&red[i4]);
        f32x4 a1 = *reinterpret_cast<const f32x4*>(&red[1024 + i4]);
        f32x4 a2 = *reinterpret_cast<const f32x4*>(&red[2048 + i4]);
        f32x4 a3 = *reinterpret_cast<const f32x4*>(&red[3072 + i4]);
        f32x4 s = (a0 + a1 + a2 + a3) * (1.0f / 512.0f);
        *reinterpret_cast<f32x4*>(&KV[((size_t)(g * 12 + grp) << 10) + i4]) = s;
    }
}

// ---------------------------------------------------------------------------
// attn_mfma: O[n][grp*32+e] = sum_d rope(q)[n][grp][d] * KV[batch[n]][grp][d][e]
// One block per (128-node chunk, grp): 3072 blocks x 256 threads (4 waves).
// VERIFIED round-10.
__global__ __launch_bounds__(256) void attn_mfma(
    u16* __restrict__ Qw, const float* __restrict__ pos,
    const int* __restrict__ batch, const float* __restrict__ freqs,
    const float* __restrict__ KV) {
    const int bid = blockIdx.x;               // 3072 = 256 chunks * 12 groups
    const int xcd = bid & 7, jj = bid >> 3;   // jj 0..383
    const int chunk = (xcd << 5) + jj / 12, grp = jj % 12;
    const int nbase = chunk << 7;

    const int tid = threadIdx.x;
    const int w = tid >> 6, lane = tid & 63;
    const int hi = lane >> 5, de = lane & 31;

    __shared__ float sfreq[48];               // this grp: 16 pairs x 3
    __shared__ __align__(16) float red[4096]; // O tile fp32 [128][32]

    if (tid < 48) sfreq[tid] = freqs[grp * 48 + tid];

    const int node = nbase + (w << 5) + de;
    const float p0 = pos[node * 3 + 0];
    const float p1 = pos[node * 3 + 1];
    const float p2 = pos[node * 3 + 2];
    const int bnode = batch[node];
    const int g0 = batch[nbase + (w << 5)];
    const int g1 = batch[nbase + (w << 5) + 31];

    // raw Q fragment: A layout row = de (node), k = hi*8+j (d within group)
    union { bf16x8 v; u16 u[8]; } qlo, qhi, alo, ahi;
    {
        const u16* qp = Qw + (size_t)node * K_DIM + (grp << 5) + (hi << 3);
        qlo.v = *reinterpret_cast<const bf16x8*>(qp);        // d = hi*8+j
        qhi.v = *reinterpret_cast<const bf16x8*>(qp + 16);   // d = 16+hi*8+j
    }
    __syncthreads();                          // sfreq visible
#pragma unroll
    for (int z = 0; z < 4; z++) {
        const int pl = (hi << 2) + z;                        // pair for lo half
        const float* F  = &sfreq[pl * 3];
        const float* F2 = &sfreq[(8 + pl) * 3];              // pair for hi half
        float sn, cs, sn2, cs2;
        __sincosf(p0 * F[0]  + p1 * F[1]  + p2 * F[2],  &sn,  &cs);
        __sincosf(p0 * F2[0] + p1 * F2[1] + p2 * F2[2], &sn2, &cs2);
        float x1 = bf2f(qlo.u[2 * z]), x2 = bf2f(qlo.u[2 * z + 1]);
        alo.u[2 * z]     = f2bf(x1 * cs - x2 * sn);
        alo.u[2 * z + 1] = f2bf(x1 * sn + x2 * cs);
        float y1 = bf2f(qhi.u[2 * z]), y2 = bf2f(qhi.u[2 * z + 1]);
        ahi.u[2 * z]     = f2bf(y1 * cs2 - y2 * sn2);
        ahi.u[2 * z + 1] = f2bf(y1 * sn2 + y2 * cs2);
    }

    f32x16 oacc;
#pragma unroll
    for (int r = 0; r < 16; r++) oacc[r] = 0.0f;
    for (int g = g0; g <= g1; g++) {
        const bool msk = (bnode == g);
        union { bf16x8 v; u16 u[8]; } ml, mh, bl, bh;
#pragma unroll
        for (int j = 0; j < 8; j++) {
            ml.u[j] = msk ? alo.u[j] : (u16)0;
            mh.u[j] = msk ? ahi.u[j] : (u16)0;
        }
        const float* kvp = KV + (((size_t)(g * 12 + grp)) << 10) + de;
#pragma unroll
        for (int j = 0; j < 8; j++) {                        // B[k=d][col=e=de]
            bl.u[j] = f2bf(kvp[(hi * 8 + j) << 5]);
            bh.u[j] = f2bf(kvp[(16 + hi * 8 + j) << 5]);
        }
        oacc = __builtin_amdgcn_mfma_f32_32x32x16_bf16(ml.v, bl.v, oacc, 0, 0, 0);
        oacc = __builtin_amdgcn_mfma_f32_32x32x16_bf16(mh.v, bh.v, oacc, 0, 0, 0);
    }

    // C/D map: col=lane&31, row=(reg&3)+8*(reg>>2)+4*(lane>>5)
#pragma unroll
    for (int r = 0; r < 16; r++) {
        int rl = (r & 3) + ((r >> 2) << 3) + (hi << 2);
        red[((w << 5) + rl) * 32 + de] = oacc[r];
    }
    __syncthreads();
    {
        const int row = tid >> 1, half = tid & 1;
        union { u16 u[16]; float4 v[2]; } pk;
#pragma unroll
        for (int z = 0; z < 16; z++)
            pk.u[z] = f2bf(red[row * 32 + half * 16 + z]);
        float4* dst = reinterpret_cast<float4*>(
            Qw + (size_t)(nbase + row) * K_DIM + (grp << 5) + (half << 4));
        dst[0] = pk.v[0];
        dst[1] = pk.v[1];
    }
}

// ---------------------------------------------------------------------------
extern "C" void kernel_launch(void* const* d_in, const int* in_sizes, int n_in,
                              void* d_out, int out_size, void* d_ws, size_t ws_size,
                              hipStream_t stream) {
    const float* x     = (const float*)d_in[0];
    const float* pos   = (const float*)d_in[1];
    const int*   batch = (const int*)d_in[2];
    const float* Wq    = (const float*)d_in[3];
    const float* bq    = (const float*)d_in[4];
    const float* Wv    = (const float*)d_in[5];
    const float* bv    = (const float*)d_in[6];
    const float* Wo    = (const float*)d_in[7];
    const float* bo    = (const float*)d_in[8];
    const float* fr    = (const float*)d_in[9];
    float* out = (float*)d_out;

    char* ws = (char*)d_ws;                   // total use ~29.2 MB
    float* KV   = (float*)(ws);               //  3,145,728 B  [g][grp][d][e] fp32
    u16*   WqvT = (u16*)(ws + 3145728);       //    589,824 B
    u16*   WoT  = (u16*)(ws + 3735552);       //    294,912 B
    u16*   Qw   = (u16*)(ws + 4030464);       // 25,165,824 B (Q, then O in-place)
    // d_out (50.3 MB fp32) doubles as scratch until gemm_out overwrites it:
    u16*   Vd   = (u16*)d_out;                // [0, 25.2 MB): V bf16
    u16*   xb   = (u16*)d_out + N_NODES * 384;// [25.2, 50.3 MB): x as bf16

    prep<<<dim3(6576), dim3(256), 0, stream>>>(x, Wq, Wv, Wo, xb, WqvT, WoT);
    gemm_qv<<<dim3(1536), dim3(256), 0, stream>>>(xb, WqvT, bq, bv, Qw, Vd);
    kv_mfma<<<dim3(768), dim3(256), 0, stream>>>(Vd, pos, batch, fr, KV);
    attn_mfma<<<dim3(3072), dim3(256), 0, stream>>>(Qw, pos, batch, fr, KV);
    gemm_out<<<dim3(768), dim3(256), 0, stream>>>(Qw, WoT, bo, out);
}